// Round 14
// baseline (224.800 us; speedup 1.0000x reference)
//
#include <hip/hip_runtime.h>
#include <math.h>

// Problem constants
#define LQ 1024
#define EQ 512
#define BQ 32
#define MQ 64

static constexpr int BCHUNK = LQ * EQ;   // 524288 floats per b-slice of d_out
// d_out overlay (per b-slice of 524288 floats), phase by phase:
//  k_trig:   Tm bf16 A-frags in slice0 floats [0, 131072)
//  k_dft4:   reads q + Tm-frags; writes SPLITX bf16 arrays 0..3 (sx_ptr) in
//            slices z=0..7 at [z][262144, 524288)  (disjoint from Tm-frags)
//  k_modes12:Opart[hs][c][i] hs=0..3 at b*BCHUNK + hs*65536  [0,262144)
//  k_inv3:   y[l][i] overwrites slice. Each block reads ONLY its own i-columns
//            of the 4 partials (staged to LDS before any write -> WAR-safe).
//
// PERF MODEL (r7..r13, 3-point validated): bound by VMEM line-requests
// (~50 64B-lines/cycle chip-wide). r13: W 2.1M + X 4.2M + O 0.5M = 6.8M ->
// 71us observed. This round: i-tile 16->32 halves X re-reads (it 32->16):
// 4.7M -> ~50us predicted. W stays dense (m-tile 16, full 64B lines).
// Also: __launch_bounds__(512,4) caps VGPR at 64 -> spill; use plain form.

typedef short short8 __attribute__((ext_vector_type(8)));
typedef float f32x4 __attribute__((ext_vector_type(4)));
typedef unsigned short ushort_t;

union FragI { int i[4]; int4 v; short8 s; };

// async global->LDS, 16B per lane; dest must be wave-uniform base (+lane*16 HW)
__device__ __forceinline__ void gload16(const float* g, float* l) {
    __builtin_amdgcn_global_load_lds(
        (const __attribute__((address_space(1))) void*)g,
        (__attribute__((address_space(3))) void*)l, 16, 0, 0);
}

// SPLITX: 4 bf16 arrays [m(64)][hblk(16)][b(32)][hh(32)], arr: 0=xrHi 1=xrLo
// 2=xiHi 3=xiLo. Flat bf16 index G = arr*2^20 + m*16384 + (h/32)*1024 + b*32
// + (h%32), mapped into 1MB-float zones: z = G>>19 at slice z offset 262144.
__device__ inline char* sx_ptr(float* dout, int arr, int m, int b, int h) {
    unsigned G = ((unsigned)arr << 20) + ((unsigned)m << 14) +
                 ((unsigned)(h >> 5) << 10) + ((unsigned)b << 5) + (unsigned)(h & 31);
    unsigned z = G >> 19, w = G & 524287u;
    return (char*)(dout + (size_t)z * BCHUNK + 262144) + (size_t)w * 2;
}

// split two fp32 into packed bf16 pairs (truncation; lo captures the residual)
__device__ inline void split2(float a, float b, unsigned& hi, unsigned& lo) {
    unsigned ua = __float_as_uint(a), ub = __float_as_uint(b);
    unsigned ha = ua & 0xFFFF0000u, hb = ub & 0xFFFF0000u;
    hi = (ua >> 16) | hb;
    float la = a - __uint_as_float(ha);
    float lb = b - __uint_as_float(hb);
    lo = (__float_as_uint(la) >> 16) | (__float_as_uint(lb) & 0xFFFF0000u);
}

__device__ inline void split1(float x, ushort_t& hi, ushort_t& lo) {
    unsigned u = __float_as_uint(x);
    hi = (ushort_t)(u >> 16);
    float r = x - __uint_as_float(u & 0xFFFF0000u);
    lo = (ushort_t)(__float_as_uint(r) >> 16);
}

// ---------------- kernel 0: trig tables (unchanged) ----------------
__global__ __launch_bounds__(256) void k_trig(unsigned* __restrict__ BFhi,
                                              unsigned* __restrict__ BFlo,
                                              float* __restrict__ dout) {
    int idx = blockIdx.x * 256 + threadIdx.x;   // 0..65535 = l*64+m
    int l = idx >> 6, m = idx & 63;
    int tt = (l * m) & (LQ - 1);
    float ang = (float)tt * 6.135923151542565e-03f;  // 2*pi/1024
    float s, c;
    sincosf(ang, &s, &c);
    float coef = (m == 0 ? 1.0f : 2.0f) * (1.0f / (float)LQ);
    float b0 = coef * c;
    float b1 = (m == 0) ? 0.0f : (-2.0f / (float)LQ) * s;
    unsigned hi, lo;
    split2(b0, b1, hi, lo);
    {
        int lt = l >> 4, kb = m >> 4, kgb = (m & 15) >> 2;
        int lane = kgb * 16 + (l & 15);
        int u = lt * 1024 + kb * 256 + lane * 4 + (m & 3);
        BFhi[u] = hi;
        BFlo[u] = lo;
    }
    ushort_t* THs = (ushort_t*)dout;
    ushort_t* TLs = (ushort_t*)(dout + 65536);
    int ks = l >> 5, kg = (l >> 3) & 3, j = l & 7;
    int mt = m >> 3;
    int lane0 = kg * 16 + 2 * (m & 7);
    ushort_t ch, cl, sh, sl;
    split1(c, ch, cl);
    split1(-s, sh, sl);
    int u0 = ((ks * 8 + mt) * 64 + lane0) * 8 + j;
    THs[u0] = ch;  TLs[u0] = cl;
    THs[u0 + 8] = sh;  TLs[u0 + 8] = sl;
}

#define MM(A, B, C) C = __builtin_amdgcn_mfma_f32_16x16x32_bf16(A, B, C, 0, 0, 0)

// ---------------- kernel 1: truncated DFT via MFMA (unchanged) ----------
__global__ __launch_bounds__(512) void k_dft4(const float* __restrict__ q,
                                              float* __restrict__ dout) {
    __shared__ float qs[2 * 2048];      // 16KB: [buf][lp 64][h 32]
    const int t    = threadIdx.x;
    const int wave = t >> 6;
    const int lane = t & 63;
    const int a    = wave & 3;
    const int ht   = wave >> 2;
    const int b    = blockIdx.x >> 4;
    const int hg   = blockIdx.x & 15;
    const int hbase = hg * 32;
    const int col  = lane & 15;
    const int kg   = lane >> 4;
    const float* qb = q + (size_t)b * BCHUNK;
    const int4* TH4 = (const int4*)dout;
    const int4* TL4 = (const int4*)(dout + 65536);

    f32x4 acc[2] = {{0.f, 0.f, 0.f, 0.f}, {0.f, 0.f, 0.f, 0.f}};
    const int lp = wave * 8 + (lane >> 3);     // slot row for gload src
    const int hq = 4 * (lane & 7);

    gload16(qb + (size_t)lp * EQ + hbase + hq, &qs[wave * 256]);

    int cur = 0;
    for (int cc = 0; cc < 16; ++cc) {
        __syncthreads();                        // q(cc) ready in buf[cur]
        FragI ah[2][2], al[2][2];
#pragma unroll
        for (int ksl = 0; ksl < 2; ++ksl)
#pragma unroll
            for (int ti = 0; ti < 2; ++ti) {
                int idx = ((cc * 2 + ksl) * 8 + 2 * a + ti) * 64 + lane;
                ah[ksl][ti].v = TH4[idx];
                al[ksl][ti].v = TL4[idx];
            }
        if (cc < 15)
            gload16(qb + (size_t)((cc + 1) * 64 + lp) * EQ + hbase + hq,
                    &qs[(cur ^ 1) * 2048 + wave * 256]);
#pragma unroll
        for (int ksl = 0; ksl < 2; ++ksl) {
            float v[8];
#pragma unroll
            for (int j = 0; j < 8; ++j)
                v[j] = qs[cur * 2048 + (ksl * 32 + kg * 8 + j) * 32 + ht * 16 + col];
            FragI bhiF, bloF;
#pragma unroll
            for (int k2 = 0; k2 < 4; ++k2) {
                unsigned h_, l_;
                split2(v[2 * k2], v[2 * k2 + 1], h_, l_);
                bhiF.i[k2] = (int)h_;
                bloF.i[k2] = (int)l_;
            }
#pragma unroll
            for (int ti = 0; ti < 2; ++ti) {
                MM(ah[ksl][ti].s, bhiF.s, acc[ti]);
                MM(ah[ksl][ti].s, bloF.s, acc[ti]);
                MM(al[ksl][ti].s, bhiF.s, acc[ti]);
            }
        }
        cur ^= 1;
    }
    const int h = hbase + ht * 16 + col;
#pragma unroll
    for (int ti = 0; ti < 2; ++ti) {
        int mt = 2 * a + ti;
        int mA = mt * 8 + kg * 2;
#pragma unroll
        for (int mi = 0; mi < 2; ++mi) {
            float xr = acc[ti][2 * mi];
            float xi = acc[ti][2 * mi + 1];
            ushort_t rh, rl, ih_, il_;
            split1(xr, rh, rl);
            split1(xi, ih_, il_);
            int m = mA + mi;
            *(ushort_t*)sx_ptr(dout, 0, m, b, h) = rh;
            *(ushort_t*)sx_ptr(dout, 1, m, b, h) = rl;
            *(ushort_t*)sx_ptr(dout, 2, m, b, h) = ih_;
            *(ushort_t*)sx_ptr(dout, 3, m, b, h) = il_;
        }
    }
}

// ---------------- kernel 2: per-mode complex GEMM, v13 (i-tile 32) ---------
// Opart[hs][b][2m+ri][i] = sum_{h in hs quarter} X[b][h][m] * W[h][i][m]
// grid 256 = hs(4) x mc(4: 16m) x it(16: 32 i). block 512 = 8 waves
// (wave w -> m-pair {m0+2w, m0+2w+1}, BOTH i-subtiles). LDS 139KB ->
// 1 block/CU, 8 waves. X loaded once per (mi,nt,kk), consumed by both
// isubs -> X line-requests halved vs r13 (the modeled bottleneck).
// W staged as full 64B lines via reg double-buffer (dense); pad 17 ->
// 16 distinct banks across cols (4-way over kg, ~free).
__global__ __launch_bounds__(512) void k_modes12(const float* __restrict__ wreal,
                                                 const float* __restrict__ wimag,
                                                 float* __restrict__ dout) {
    __shared__ float Wlds[2 * 32 * 32 * 17];   // 139264 B
    const int t    = threadIdx.x;
    const int wave = t >> 6;
    const int lane = t & 63;
    const int blk  = blockIdx.x;
    const int hs   = blk >> 6;           // 0..3
    const int mc   = (blk >> 4) & 3;
    const int it   = blk & 15;
    const int i0   = it * 32;
    const int m0   = mc * 16;
    const int col  = lane & 15;          // A row (i within subtile) / B col (b)
    const int kg   = lane >> 4;          // k-group
    const int hbase = hs * 128;

    const char* xp0 = sx_ptr(dout, 0, m0 + 2 * wave, col, hbase + kg * 8);

    f32x4 zero4 = {0.f, 0.f, 0.f, 0.f};
    f32x4 acc[2][2][2][2];               // [isub][mi][part][nt] = 64 VGPR
#pragma unroll
    for (int s_ = 0; s_ < 2; ++s_)
#pragma unroll
        for (int a = 0; a < 2; ++a)
#pragma unroll
            for (int bq = 0; bq < 2; ++bq)
#pragma unroll
                for (int c = 0; c < 2; ++c) acc[s_][a][bq][c] = zero4;

    float2 st[32];                       // staging regs (double-buffer)
#define LOADK(KK)                                                             \
    {                                                                         \
        int h0_ = hbase + (KK) * 32;                                          \
        _Pragma("unroll")                                                     \
        for (int r = 0; r < 32; ++r) {                                        \
            int e = r * 512 + t;                                              \
            int m2 = e & 7, ii = (e >> 3) & 31, hh = (e >> 8) & 31;           \
            const float* src = (e >> 13) ? wimag : wreal;                     \
            st[r] = *(const float2*)&src[(size_t)(h0_ + hh) * 32768 +         \
                                         (size_t)(i0 + ii) * 64 + m0 + 2 * m2]; \
        }                                                                     \
    }

    LOADK(0);
    for (int kk = 0; kk < 4; ++kk) {
#pragma unroll
        for (int r = 0; r < 32; ++r) {
            int e = r * 512 + t;
            int m2 = e & 7, ii = (e >> 3) & 31, hh = (e >> 8) & 31;
            int part = e >> 13;
            *(float2*)&Wlds[(((part * 32 + hh) * 32) + ii) * 17 + 2 * m2] = st[r];
        }
        __syncthreads();
        if (kk < 3) LOADK(kk + 1);       // prefetch next chunk under compute
#pragma unroll
        for (int mi = 0; mi < 2; ++mi) {
            const int mloc = 2 * wave + mi;
            // X for this (mi,kk): both nt groups, shared across both isubs
            short8 bX[2][4];
            const char* xpm = xp0 + (size_t)mi * 32768 + (size_t)kk * 2048;
#pragma unroll
            for (int nt = 0; nt < 2; ++nt)
#pragma unroll
                for (int arr = 0; arr < 4; ++arr) {
                    FragI f;
                    f.v = *(const int4*)(xpm + (size_t)arr * 4194304 +
                                         (size_t)nt * 1024);
                    bX[nt][arr] = f.s;
                }
#pragma unroll
            for (int isub = 0; isub < 2; ++isub) {
                short8 aW[2][2];         // [part][prec]: 0=Wr 1=Wi
                short8 nW[2];            // negated Wi hi/lo (exact sign flip)
#pragma unroll
                for (int part = 0; part < 2; ++part) {
                    float v[8];
#pragma unroll
                    for (int j = 0; j < 8; ++j)
                        v[j] = Wlds[((part * 32 + kg * 8 + j) * 32 +
                                     isub * 16 + col) * 17 + mloc];
                    FragI hiF, loF;
#pragma unroll
                    for (int k = 0; k < 4; ++k) {
                        unsigned h, l;
                        split2(v[2 * k], v[2 * k + 1], h, l);
                        hiF.i[k] = (int)h;
                        loF.i[k] = (int)l;
                    }
                    aW[part][0] = hiF.s;
                    aW[part][1] = loF.s;
                    if (part == 1) {
                        FragI nh, nl;
#pragma unroll
                        for (int k = 0; k < 4; ++k) {
                            nh.i[k] = hiF.i[k] ^ 0x80008000;
                            nl.i[k] = loF.i[k] ^ 0x80008000;
                        }
                        nW[0] = nh.s;
                        nW[1] = nl.s;
                    }
                }
#pragma unroll
                for (int nt = 0; nt < 2; ++nt) {
                    // out_r = Wr*xr + (-Wi)*xi   (3-term split each)
                    MM(aW[0][0], bX[nt][0], acc[isub][mi][0][nt]);
                    MM(aW[0][0], bX[nt][1], acc[isub][mi][0][nt]);
                    MM(aW[0][1], bX[nt][0], acc[isub][mi][0][nt]);
                    MM(nW[0],    bX[nt][2], acc[isub][mi][0][nt]);
                    MM(nW[0],    bX[nt][3], acc[isub][mi][0][nt]);
                    MM(nW[1],    bX[nt][2], acc[isub][mi][0][nt]);
                    // out_i = Wr*xi + Wi*xr
                    MM(aW[0][0], bX[nt][2], acc[isub][mi][1][nt]);
                    MM(aW[0][0], bX[nt][3], acc[isub][mi][1][nt]);
                    MM(aW[0][1], bX[nt][2], acc[isub][mi][1][nt]);
                    MM(aW[1][0], bX[nt][0], acc[isub][mi][1][nt]);
                    MM(aW[1][0], bX[nt][1], acc[isub][mi][1][nt]);
                    MM(aW[1][1], bX[nt][0], acc[isub][mi][1][nt]);
                }
            }
        }
        __syncthreads();
    }
#undef LOADK
    // epilogue: D row = i = i0 + isub*16 + kg*4 + reg (contig float4), col = b
#pragma unroll
    for (int isub = 0; isub < 2; ++isub)
#pragma unroll
        for (int mi = 0; mi < 2; ++mi)
#pragma unroll
            for (int part = 0; part < 2; ++part)
#pragma unroll
                for (int nt = 0; nt < 2; ++nt) {
                    int bb = nt * 16 + col;
                    int c = 2 * (m0 + 2 * wave + mi) + part;
                    f32x4 vv = acc[isub][mi][part][nt];
                    float4 o = make_float4(vv.x, vv.y, vv.z, vv.w);
                    *(float4*)&dout[(size_t)bb * BCHUNK + (size_t)hs * 65536 +
                                    (size_t)c * EQ + i0 + isub * 16 + kg * 4] = o;
                }
}

// ---------------- kernel 3: truncated irfft via MFMA (unchanged) ----------
__global__ __launch_bounds__(256) void k_inv3(const unsigned* __restrict__ BFhi,
                                              const unsigned* __restrict__ BFlo,
                                              float* __restrict__ dout) {
    __shared__ unsigned Bf[4096];   // [hilo(2)][nt(2)][kb(4)][lane(64)][4] 16KB
    const int t    = threadIdx.x;
    const int wave = t >> 6;
    const int lane = t & 63;
    const int b    = blockIdx.x >> 4;
    const int it   = blockIdx.x & 15;
    const int i0   = it * 32;
    float* base = dout + (size_t)b * BCHUNK;

#pragma unroll
    for (int r = 0; r < 8; ++r) {
        int idx = r * 256 + t;               // 2048 = 64 c-pairs x 32 i
        int il = idx & 31, cp = idx >> 5;
        int c0 = 2 * cp;
        const float* p0 = base + (size_t)c0 * EQ + i0 + il;
        float s0 = p0[0] + p0[65536] + p0[2 * 65536] + p0[3 * 65536];
        const float* p1 = p0 + EQ;
        float s1 = p1[0] + p1[65536] + p1[2 * 65536] + p1[3 * 65536];
        unsigned hi, lo;
        split2(s0, s1, hi, lo);
        int nt = il >> 4, i_loc = il & 15;
        int kb = c0 >> 5, kg = (c0 & 31) >> 3, jp = (c0 & 7) >> 1;
        int u = (nt * 4 + kb) * 256 + (kg * 16 + i_loc) * 4 + jp;
        Bf[u] = hi;
        Bf[2048 + u] = lo;
    }
    __syncthreads();
    FragI bh[2][4], bl[2][4];
#pragma unroll
    for (int nt = 0; nt < 2; ++nt)
#pragma unroll
        for (int kb = 0; kb < 4; ++kb) {
            bh[nt][kb].v = *(const int4*)&Bf[(nt * 4 + kb) * 256 + lane * 4];
            bl[nt][kb].v = *(const int4*)&Bf[2048 + (nt * 4 + kb) * 256 + lane * 4];
        }
    for (int r = 0; r < 16; ++r) {
        int lt = wave + 4 * r;
        FragI ah[4], al[4];
#pragma unroll
        for (int kb = 0; kb < 4; ++kb) {
            ah[kb].v = *(const int4*)&BFhi[lt * 1024 + kb * 256 + lane * 4];
            al[kb].v = *(const int4*)&BFlo[lt * 1024 + kb * 256 + lane * 4];
        }
        f32x4 a0 = {0.f, 0.f, 0.f, 0.f}, a1 = {0.f, 0.f, 0.f, 0.f};
#pragma unroll
        for (int kb = 0; kb < 4; ++kb) {
            MM(ah[kb].s, bh[0][kb].s, a0);
            MM(ah[kb].s, bl[0][kb].s, a0);
            MM(al[kb].s, bh[0][kb].s, a0);
            MM(ah[kb].s, bh[1][kb].s, a1);
            MM(ah[kb].s, bl[1][kb].s, a1);
            MM(al[kb].s, bh[1][kb].s, a1);
        }
        int lrow = lt * 16 + (lane >> 4) * 4;
        int icol = i0 + (lane & 15);
#pragma unroll
        for (int j = 0; j < 4; ++j) {
            base[(size_t)(lrow + j) * EQ + icol]      = a0[j];
            base[(size_t)(lrow + j) * EQ + icol + 16] = a1[j];
        }
    }
}
#undef MM

extern "C" void kernel_launch(void* const* d_in, const int* in_sizes, int n_in,
                              void* d_out, int out_size, void* d_ws, size_t ws_size,
                              hipStream_t stream) {
    const float* q  = (const float*)d_in[0];
    const float* wr = (const float*)d_in[1];
    const float* wi = (const float*)d_in[2];
    float* out = (float*)d_out;
    unsigned* BFhi = (unsigned*)d_ws;           // u32 [0, 65536)
    unsigned* BFlo = BFhi + 65536;              // u32 [65536, 131072)

    hipLaunchKernelGGL(k_trig,    dim3(256), dim3(256), 0, stream, BFhi, BFlo, out);
    hipLaunchKernelGGL(k_dft4,    dim3(512), dim3(512), 0, stream, q, out);
    hipLaunchKernelGGL(k_modes12, dim3(256), dim3(512), 0, stream, wr, wi, out);
    hipLaunchKernelGGL(k_inv3,    dim3(512), dim3(256), 0, stream, BFhi, BFlo, out);
}

// Round 15
// 220.395 us; speedup vs baseline: 1.0200x; 1.0200x over previous
//
#include <hip/hip_runtime.h>
#include <math.h>

// Problem constants
#define LQ 1024
#define EQ 512
#define BQ 32
#define MQ 64

static constexpr int BCHUNK = LQ * EQ;   // 524288 floats per b-slice of d_out
// d_out overlay (per b-slice of 524288 floats), phase by phase:
//  k_trig:   Tm bf16 A-frags in slice0 floats [0, 131072)
//  k_dft4:   reads q + Tm-frags; writes SPLITX bf16 arrays 0..3 (sx_ptr) in
//            slices z=0..7 at [z][262144, 524288)  (disjoint from Tm-frags)
//  k_modes13:Opart[hs][c][i] hs=0..3 at b*BCHUNK + hs*65536  [0,262144)
//  k_inv3:   y[l][i] overwrites slice. Each block reads ONLY its own i-columns
//            of the 4 partials (staged to LDS before any write -> WAR-safe).
//
// PERF MODEL (r7..r14, 4-point validated): bound by VMEM line-requests
// (~50 64B-lines/cycle chip-wide). r13: 6.8M lines -> 71us. i-tile 32
// halves X re-reads: 4.7M -> ~50us predicted. r14 failed ONLY from VGPR
// spill (128-cap with ~190 live; FETCH +95MB scratch). LDS 139KB already
// forces 1 block/CU (2 waves/SIMD) where 256 VGPR is free ->
// __launch_bounds__(512, 1) lifts the cap. ((512,4) empirically -> 64 VGPR.)

typedef short short8 __attribute__((ext_vector_type(8)));
typedef float f32x4 __attribute__((ext_vector_type(4)));
typedef unsigned short ushort_t;

union FragI { int i[4]; int4 v; short8 s; };

// async global->LDS, 16B per lane; dest must be wave-uniform base (+lane*16 HW)
__device__ __forceinline__ void gload16(const float* g, float* l) {
    __builtin_amdgcn_global_load_lds(
        (const __attribute__((address_space(1))) void*)g,
        (__attribute__((address_space(3))) void*)l, 16, 0, 0);
}

// SPLITX: 4 bf16 arrays [m(64)][hblk(16)][b(32)][hh(32)], arr: 0=xrHi 1=xrLo
// 2=xiHi 3=xiLo. Flat bf16 index G = arr*2^20 + m*16384 + (h/32)*1024 + b*32
// + (h%32), mapped into 1MB-float zones: z = G>>19 at slice z offset 262144.
__device__ inline char* sx_ptr(float* dout, int arr, int m, int b, int h) {
    unsigned G = ((unsigned)arr << 20) + ((unsigned)m << 14) +
                 ((unsigned)(h >> 5) << 10) + ((unsigned)b << 5) + (unsigned)(h & 31);
    unsigned z = G >> 19, w = G & 524287u;
    return (char*)(dout + (size_t)z * BCHUNK + 262144) + (size_t)w * 2;
}

// split two fp32 into packed bf16 pairs (truncation; lo captures the residual)
__device__ inline void split2(float a, float b, unsigned& hi, unsigned& lo) {
    unsigned ua = __float_as_uint(a), ub = __float_as_uint(b);
    unsigned ha = ua & 0xFFFF0000u, hb = ub & 0xFFFF0000u;
    hi = (ua >> 16) | hb;
    float la = a - __uint_as_float(ha);
    float lb = b - __uint_as_float(hb);
    lo = (__float_as_uint(la) >> 16) | (__float_as_uint(lb) & 0xFFFF0000u);
}

__device__ inline void split1(float x, ushort_t& hi, ushort_t& lo) {
    unsigned u = __float_as_uint(x);
    hi = (ushort_t)(u >> 16);
    float r = x - __uint_as_float(u & 0xFFFF0000u);
    lo = (ushort_t)(__float_as_uint(r) >> 16);
}

// ---------------- kernel 0: trig tables (unchanged) ----------------
__global__ __launch_bounds__(256) void k_trig(unsigned* __restrict__ BFhi,
                                              unsigned* __restrict__ BFlo,
                                              float* __restrict__ dout) {
    int idx = blockIdx.x * 256 + threadIdx.x;   // 0..65535 = l*64+m
    int l = idx >> 6, m = idx & 63;
    int tt = (l * m) & (LQ - 1);
    float ang = (float)tt * 6.135923151542565e-03f;  // 2*pi/1024
    float s, c;
    sincosf(ang, &s, &c);
    float coef = (m == 0 ? 1.0f : 2.0f) * (1.0f / (float)LQ);
    float b0 = coef * c;
    float b1 = (m == 0) ? 0.0f : (-2.0f / (float)LQ) * s;
    unsigned hi, lo;
    split2(b0, b1, hi, lo);
    {
        int lt = l >> 4, kb = m >> 4, kgb = (m & 15) >> 2;
        int lane = kgb * 16 + (l & 15);
        int u = lt * 1024 + kb * 256 + lane * 4 + (m & 3);
        BFhi[u] = hi;
        BFlo[u] = lo;
    }
    ushort_t* THs = (ushort_t*)dout;
    ushort_t* TLs = (ushort_t*)(dout + 65536);
    int ks = l >> 5, kg = (l >> 3) & 3, j = l & 7;
    int mt = m >> 3;
    int lane0 = kg * 16 + 2 * (m & 7);
    ushort_t ch, cl, sh, sl;
    split1(c, ch, cl);
    split1(-s, sh, sl);
    int u0 = ((ks * 8 + mt) * 64 + lane0) * 8 + j;
    THs[u0] = ch;  TLs[u0] = cl;
    THs[u0 + 8] = sh;  TLs[u0 + 8] = sl;
}

#define MM(A, B, C) C = __builtin_amdgcn_mfma_f32_16x16x32_bf16(A, B, C, 0, 0, 0)

// ---------------- kernel 1: truncated DFT via MFMA (unchanged) ----------
__global__ __launch_bounds__(512) void k_dft4(const float* __restrict__ q,
                                              float* __restrict__ dout) {
    __shared__ float qs[2 * 2048];      // 16KB: [buf][lp 64][h 32]
    const int t    = threadIdx.x;
    const int wave = t >> 6;
    const int lane = t & 63;
    const int a    = wave & 3;
    const int ht   = wave >> 2;
    const int b    = blockIdx.x >> 4;
    const int hg   = blockIdx.x & 15;
    const int hbase = hg * 32;
    const int col  = lane & 15;
    const int kg   = lane >> 4;
    const float* qb = q + (size_t)b * BCHUNK;
    const int4* TH4 = (const int4*)dout;
    const int4* TL4 = (const int4*)(dout + 65536);

    f32x4 acc[2] = {{0.f, 0.f, 0.f, 0.f}, {0.f, 0.f, 0.f, 0.f}};
    const int lp = wave * 8 + (lane >> 3);     // slot row for gload src
    const int hq = 4 * (lane & 7);

    gload16(qb + (size_t)lp * EQ + hbase + hq, &qs[wave * 256]);

    int cur = 0;
    for (int cc = 0; cc < 16; ++cc) {
        __syncthreads();                        // q(cc) ready in buf[cur]
        FragI ah[2][2], al[2][2];
#pragma unroll
        for (int ksl = 0; ksl < 2; ++ksl)
#pragma unroll
            for (int ti = 0; ti < 2; ++ti) {
                int idx = ((cc * 2 + ksl) * 8 + 2 * a + ti) * 64 + lane;
                ah[ksl][ti].v = TH4[idx];
                al[ksl][ti].v = TL4[idx];
            }
        if (cc < 15)
            gload16(qb + (size_t)((cc + 1) * 64 + lp) * EQ + hbase + hq,
                    &qs[(cur ^ 1) * 2048 + wave * 256]);
#pragma unroll
        for (int ksl = 0; ksl < 2; ++ksl) {
            float v[8];
#pragma unroll
            for (int j = 0; j < 8; ++j)
                v[j] = qs[cur * 2048 + (ksl * 32 + kg * 8 + j) * 32 + ht * 16 + col];
            FragI bhiF, bloF;
#pragma unroll
            for (int k2 = 0; k2 < 4; ++k2) {
                unsigned h_, l_;
                split2(v[2 * k2], v[2 * k2 + 1], h_, l_);
                bhiF.i[k2] = (int)h_;
                bloF.i[k2] = (int)l_;
            }
#pragma unroll
            for (int ti = 0; ti < 2; ++ti) {
                MM(ah[ksl][ti].s, bhiF.s, acc[ti]);
                MM(ah[ksl][ti].s, bloF.s, acc[ti]);
                MM(al[ksl][ti].s, bhiF.s, acc[ti]);
            }
        }
        cur ^= 1;
    }
    const int h = hbase + ht * 16 + col;
#pragma unroll
    for (int ti = 0; ti < 2; ++ti) {
        int mt = 2 * a + ti;
        int mA = mt * 8 + kg * 2;
#pragma unroll
        for (int mi = 0; mi < 2; ++mi) {
            float xr = acc[ti][2 * mi];
            float xi = acc[ti][2 * mi + 1];
            ushort_t rh, rl, ih_, il_;
            split1(xr, rh, rl);
            split1(xi, ih_, il_);
            int m = mA + mi;
            *(ushort_t*)sx_ptr(dout, 0, m, b, h) = rh;
            *(ushort_t*)sx_ptr(dout, 1, m, b, h) = rl;
            *(ushort_t*)sx_ptr(dout, 2, m, b, h) = ih_;
            *(ushort_t*)sx_ptr(dout, 3, m, b, h) = il_;
        }
    }
}

// ---------------- kernel 2: per-mode complex GEMM, v14 (i-tile 32, no spill)
// Opart[hs][b][2m+ri][i] = sum_{h in hs quarter} X[b][h][m] * W[h][i][m]
// grid 256 = hs(4) x mc(4: 16m) x it(16: 32 i). block 512 = 8 waves
// (wave w -> m-pair {m0+2w, m0+2w+1}, BOTH i-subtiles). LDS 139KB ->
// 1 block/CU (2 waves/SIMD) -> 256 VGPR per wave is free:
// __launch_bounds__(512, 1) lifts the compiler's 128-VGPR default that
// caused r14's spill (FETCH +95MB scratch). X loaded once per (mi,nt,kk),
// consumed by both isubs -> X line-requests halved vs r13.
__global__ __launch_bounds__(512, 1) void k_modes13(const float* __restrict__ wreal,
                                                    const float* __restrict__ wimag,
                                                    float* __restrict__ dout) {
    __shared__ float Wlds[2 * 32 * 32 * 17];   // 139264 B
    const int t    = threadIdx.x;
    const int wave = t >> 6;
    const int lane = t & 63;
    const int blk  = blockIdx.x;
    const int hs   = blk >> 6;           // 0..3
    const int mc   = (blk >> 4) & 3;
    const int it   = blk & 15;
    const int i0   = it * 32;
    const int m0   = mc * 16;
    const int col  = lane & 15;          // A row (i within subtile) / B col (b)
    const int kg   = lane >> 4;          // k-group
    const int hbase = hs * 128;

    const char* xp0 = sx_ptr(dout, 0, m0 + 2 * wave, col, hbase + kg * 8);

    f32x4 zero4 = {0.f, 0.f, 0.f, 0.f};
    f32x4 acc[2][2][2][2];               // [isub][mi][part][nt] = 64 VGPR
#pragma unroll
    for (int s_ = 0; s_ < 2; ++s_)
#pragma unroll
        for (int a = 0; a < 2; ++a)
#pragma unroll
            for (int bq = 0; bq < 2; ++bq)
#pragma unroll
                for (int c = 0; c < 2; ++c) acc[s_][a][bq][c] = zero4;

    float2 st[32];                       // staging regs (double-buffer)
#define LOADK(KK)                                                             \
    {                                                                         \
        int h0_ = hbase + (KK) * 32;                                          \
        _Pragma("unroll")                                                     \
        for (int r = 0; r < 32; ++r) {                                        \
            int e = r * 512 + t;                                              \
            int m2 = e & 7, ii = (e >> 3) & 31, hh = (e >> 8) & 31;           \
            const float* src = (e >> 13) ? wimag : wreal;                     \
            st[r] = *(const float2*)&src[(size_t)(h0_ + hh) * 32768 +         \
                                         (size_t)(i0 + ii) * 64 + m0 + 2 * m2]; \
        }                                                                     \
    }

    LOADK(0);
    for (int kk = 0; kk < 4; ++kk) {
#pragma unroll
        for (int r = 0; r < 32; ++r) {
            int e = r * 512 + t;
            int m2 = e & 7, ii = (e >> 3) & 31, hh = (e >> 8) & 31;
            int part = e >> 13;
            *(float2*)&Wlds[(((part * 32 + hh) * 32) + ii) * 17 + 2 * m2] = st[r];
        }
        __syncthreads();
        if (kk < 3) LOADK(kk + 1);       // prefetch next chunk under compute
#pragma unroll
        for (int mi = 0; mi < 2; ++mi) {
            // X for this (mi,kk): both nt groups, shared across both isubs
            short8 bX[2][4];
            const char* xpm = xp0 + (size_t)mi * 32768 + (size_t)kk * 2048;
#pragma unroll
            for (int nt = 0; nt < 2; ++nt)
#pragma unroll
                for (int arr = 0; arr < 4; ++arr) {
                    FragI f;
                    f.v = *(const int4*)(xpm + (size_t)arr * 4194304 +
                                         (size_t)nt * 1024);
                    bX[nt][arr] = f.s;
                }
            const int mloc = 2 * wave + mi;
#pragma unroll
            for (int isub = 0; isub < 2; ++isub) {
                short8 aW[2][2];         // [part][prec]: 0=Wr 1=Wi
                short8 nW[2];            // negated Wi hi/lo (exact sign flip)
#pragma unroll
                for (int part = 0; part < 2; ++part) {
                    float v[8];
#pragma unroll
                    for (int j = 0; j < 8; ++j)
                        v[j] = Wlds[((part * 32 + kg * 8 + j) * 32 +
                                     isub * 16 + col) * 17 + mloc];
                    FragI hiF, loF;
#pragma unroll
                    for (int k = 0; k < 4; ++k) {
                        unsigned h, l;
                        split2(v[2 * k], v[2 * k + 1], h, l);
                        hiF.i[k] = (int)h;
                        loF.i[k] = (int)l;
                    }
                    aW[part][0] = hiF.s;
                    aW[part][1] = loF.s;
                    if (part == 1) {
                        FragI nh, nl;
#pragma unroll
                        for (int k = 0; k < 4; ++k) {
                            nh.i[k] = hiF.i[k] ^ 0x80008000;
                            nl.i[k] = loF.i[k] ^ 0x80008000;
                        }
                        nW[0] = nh.s;
                        nW[1] = nl.s;
                    }
                }
#pragma unroll
                for (int nt = 0; nt < 2; ++nt) {
                    // out_r = Wr*xr + (-Wi)*xi   (3-term split each)
                    MM(aW[0][0], bX[nt][0], acc[isub][mi][0][nt]);
                    MM(aW[0][0], bX[nt][1], acc[isub][mi][0][nt]);
                    MM(aW[0][1], bX[nt][0], acc[isub][mi][0][nt]);
                    MM(nW[0],    bX[nt][2], acc[isub][mi][0][nt]);
                    MM(nW[0],    bX[nt][3], acc[isub][mi][0][nt]);
                    MM(nW[1],    bX[nt][2], acc[isub][mi][0][nt]);
                    // out_i = Wr*xi + Wi*xr
                    MM(aW[0][0], bX[nt][2], acc[isub][mi][1][nt]);
                    MM(aW[0][0], bX[nt][3], acc[isub][mi][1][nt]);
                    MM(aW[0][1], bX[nt][2], acc[isub][mi][1][nt]);
                    MM(aW[1][0], bX[nt][0], acc[isub][mi][1][nt]);
                    MM(aW[1][0], bX[nt][1], acc[isub][mi][1][nt]);
                    MM(aW[1][1], bX[nt][0], acc[isub][mi][1][nt]);
                }
            }
        }
        __syncthreads();
    }
#undef LOADK
    // epilogue: D row = i = i0 + isub*16 + kg*4 + reg (contig float4), col = b
#pragma unroll
    for (int isub = 0; isub < 2; ++isub)
#pragma unroll
        for (int mi = 0; mi < 2; ++mi)
#pragma unroll
            for (int part = 0; part < 2; ++part)
#pragma unroll
                for (int nt = 0; nt < 2; ++nt) {
                    int bb = nt * 16 + col;
                    int c = 2 * (m0 + 2 * wave + mi) + part;
                    f32x4 vv = acc[isub][mi][part][nt];
                    float4 o = make_float4(vv.x, vv.y, vv.z, vv.w);
                    *(float4*)&dout[(size_t)bb * BCHUNK + (size_t)hs * 65536 +
                                    (size_t)c * EQ + i0 + isub * 16 + kg * 4] = o;
                }
}

// ---------------- kernel 3: truncated irfft via MFMA (unchanged) ----------
__global__ __launch_bounds__(256) void k_inv3(const unsigned* __restrict__ BFhi,
                                              const unsigned* __restrict__ BFlo,
                                              float* __restrict__ dout) {
    __shared__ unsigned Bf[4096];   // [hilo(2)][nt(2)][kb(4)][lane(64)][4] 16KB
    const int t    = threadIdx.x;
    const int wave = t >> 6;
    const int lane = t & 63;
    const int b    = blockIdx.x >> 4;
    const int it   = blockIdx.x & 15;
    const int i0   = it * 32;
    float* base = dout + (size_t)b * BCHUNK;

#pragma unroll
    for (int r = 0; r < 8; ++r) {
        int idx = r * 256 + t;               // 2048 = 64 c-pairs x 32 i
        int il = idx & 31, cp = idx >> 5;
        int c0 = 2 * cp;
        const float* p0 = base + (size_t)c0 * EQ + i0 + il;
        float s0 = p0[0] + p0[65536] + p0[2 * 65536] + p0[3 * 65536];
        const float* p1 = p0 + EQ;
        float s1 = p1[0] + p1[65536] + p1[2 * 65536] + p1[3 * 65536];
        unsigned hi, lo;
        split2(s0, s1, hi, lo);
        int nt = il >> 4, i_loc = il & 15;
        int kb = c0 >> 5, kg = (c0 & 31) >> 3, jp = (c0 & 7) >> 1;
        int u = (nt * 4 + kb) * 256 + (kg * 16 + i_loc) * 4 + jp;
        Bf[u] = hi;
        Bf[2048 + u] = lo;
    }
    __syncthreads();
    FragI bh[2][4], bl[2][4];
#pragma unroll
    for (int nt = 0; nt < 2; ++nt)
#pragma unroll
        for (int kb = 0; kb < 4; ++kb) {
            bh[nt][kb].v = *(const int4*)&Bf[(nt * 4 + kb) * 256 + lane * 4];
            bl[nt][kb].v = *(const int4*)&Bf[2048 + (nt * 4 + kb) * 256 + lane * 4];
        }
    for (int r = 0; r < 16; ++r) {
        int lt = wave + 4 * r;
        FragI ah[4], al[4];
#pragma unroll
        for (int kb = 0; kb < 4; ++kb) {
            ah[kb].v = *(const int4*)&BFhi[lt * 1024 + kb * 256 + lane * 4];
            al[kb].v = *(const int4*)&BFlo[lt * 1024 + kb * 256 + lane * 4];
        }
        f32x4 a0 = {0.f, 0.f, 0.f, 0.f}, a1 = {0.f, 0.f, 0.f, 0.f};
#pragma unroll
        for (int kb = 0; kb < 4; ++kb) {
            MM(ah[kb].s, bh[0][kb].s, a0);
            MM(ah[kb].s, bl[0][kb].s, a0);
            MM(al[kb].s, bh[0][kb].s, a0);
            MM(ah[kb].s, bh[1][kb].s, a1);
            MM(ah[kb].s, bl[1][kb].s, a1);
            MM(al[kb].s, bh[1][kb].s, a1);
        }
        int lrow = lt * 16 + (lane >> 4) * 4;
        int icol = i0 + (lane & 15);
#pragma unroll
        for (int j = 0; j < 4; ++j) {
            base[(size_t)(lrow + j) * EQ + icol]      = a0[j];
            base[(size_t)(lrow + j) * EQ + icol + 16] = a1[j];
        }
    }
}
#undef MM

extern "C" void kernel_launch(void* const* d_in, const int* in_sizes, int n_in,
                              void* d_out, int out_size, void* d_ws, size_t ws_size,
                              hipStream_t stream) {
    const float* q  = (const float*)d_in[0];
    const float* wr = (const float*)d_in[1];
    const float* wi = (const float*)d_in[2];
    float* out = (float*)d_out;
    unsigned* BFhi = (unsigned*)d_ws;           // u32 [0, 65536)
    unsigned* BFlo = BFhi + 65536;              // u32 [65536, 131072)

    hipLaunchKernelGGL(k_trig,    dim3(256), dim3(256), 0, stream, BFhi, BFlo, out);
    hipLaunchKernelGGL(k_dft4,    dim3(512), dim3(512), 0, stream, q, out);
    hipLaunchKernelGGL(k_modes13, dim3(256), dim3(512), 0, stream, wr, wi, out);
    hipLaunchKernelGGL(k_inv3,    dim3(512), dim3(256), 0, stream, BFhi, BFlo, out);
}

// Round 16
// 216.395 us; speedup vs baseline: 1.0388x; 1.0185x over previous
//
#include <hip/hip_runtime.h>
#include <math.h>

// Problem constants
#define LQ 1024
#define EQ 512
#define BQ 32
#define MQ 64

static constexpr int BCHUNK = LQ * EQ;   // 524288 floats per b-slice of d_out
// d_out overlay (per b-slice of 524288 floats), phase by phase:
//  k_trig:   Tm bf16 A-frags in slice0 floats [0, 131072)
//  k_dft4:   reads q + Tm-frags; writes SPLITX bf16 arrays 0..3 (sx_ptr) in
//            slices z=0..7 at [z][262144, 524288)  (disjoint from Tm-frags)
//  k_modes14:Opart[hs][c][i] hs=0..3 at b*BCHUNK + hs*65536  [0,262144)
//  k_inv3:   y[l][i] overwrites slice. Each block reads ONLY its own i-columns
//            of the 4 partials (staged to LDS before any write -> WAR-safe).
//
// PERF MODEL (r7..r15, 5-point validated): bound by VMEM line-requests
// (~50 64B-lines/cycle chip-wide; time ~ 9.2us per M-lines). r13: 6.8M ->
// 71us. i-tile 32 halves X: 4.7M -> ~48us. r14/r15 lesson: 512-thread
// kernels are HARD-CAPPED at 128 VGPR on this toolchain (launch_bounds
// (512,1) did NOT lift it; (512,4) caps at 64) -> i-tile 32 must FIT in
// 128: 1024-thread block, ONE m per wave (acc 32 + st 32 + bX 16 + aW 16).

typedef short short8 __attribute__((ext_vector_type(8)));
typedef float f32x4 __attribute__((ext_vector_type(4)));
typedef unsigned short ushort_t;

union FragI { int i[4]; int4 v; short8 s; };

// async global->LDS, 16B per lane; dest must be wave-uniform base (+lane*16 HW)
__device__ __forceinline__ void gload16(const float* g, float* l) {
    __builtin_amdgcn_global_load_lds(
        (const __attribute__((address_space(1))) void*)g,
        (__attribute__((address_space(3))) void*)l, 16, 0, 0);
}

// SPLITX: 4 bf16 arrays [m(64)][hblk(16)][b(32)][hh(32)], arr: 0=xrHi 1=xrLo
// 2=xiHi 3=xiLo. Flat bf16 index G = arr*2^20 + m*16384 + (h/32)*1024 + b*32
// + (h%32), mapped into 1MB-float zones: z = G>>19 at slice z offset 262144.
__device__ inline char* sx_ptr(float* dout, int arr, int m, int b, int h) {
    unsigned G = ((unsigned)arr << 20) + ((unsigned)m << 14) +
                 ((unsigned)(h >> 5) << 10) + ((unsigned)b << 5) + (unsigned)(h & 31);
    unsigned z = G >> 19, w = G & 524287u;
    return (char*)(dout + (size_t)z * BCHUNK + 262144) + (size_t)w * 2;
}

// split two fp32 into packed bf16 pairs (truncation; lo captures the residual)
__device__ inline void split2(float a, float b, unsigned& hi, unsigned& lo) {
    unsigned ua = __float_as_uint(a), ub = __float_as_uint(b);
    unsigned ha = ua & 0xFFFF0000u, hb = ub & 0xFFFF0000u;
    hi = (ua >> 16) | hb;
    float la = a - __uint_as_float(ha);
    float lb = b - __uint_as_float(hb);
    lo = (__float_as_uint(la) >> 16) | (__float_as_uint(lb) & 0xFFFF0000u);
}

__device__ inline void split1(float x, ushort_t& hi, ushort_t& lo) {
    unsigned u = __float_as_uint(x);
    hi = (ushort_t)(u >> 16);
    float r = x - __uint_as_float(u & 0xFFFF0000u);
    lo = (ushort_t)(__float_as_uint(r) >> 16);
}

// ---------------- kernel 0: trig tables (unchanged) ----------------
__global__ __launch_bounds__(256) void k_trig(unsigned* __restrict__ BFhi,
                                              unsigned* __restrict__ BFlo,
                                              float* __restrict__ dout) {
    int idx = blockIdx.x * 256 + threadIdx.x;   // 0..65535 = l*64+m
    int l = idx >> 6, m = idx & 63;
    int tt = (l * m) & (LQ - 1);
    float ang = (float)tt * 6.135923151542565e-03f;  // 2*pi/1024
    float s, c;
    sincosf(ang, &s, &c);
    float coef = (m == 0 ? 1.0f : 2.0f) * (1.0f / (float)LQ);
    float b0 = coef * c;
    float b1 = (m == 0) ? 0.0f : (-2.0f / (float)LQ) * s;
    unsigned hi, lo;
    split2(b0, b1, hi, lo);
    {
        int lt = l >> 4, kb = m >> 4, kgb = (m & 15) >> 2;
        int lane = kgb * 16 + (l & 15);
        int u = lt * 1024 + kb * 256 + lane * 4 + (m & 3);
        BFhi[u] = hi;
        BFlo[u] = lo;
    }
    ushort_t* THs = (ushort_t*)dout;
    ushort_t* TLs = (ushort_t*)(dout + 65536);
    int ks = l >> 5, kg = (l >> 3) & 3, j = l & 7;
    int mt = m >> 3;
    int lane0 = kg * 16 + 2 * (m & 7);
    ushort_t ch, cl, sh, sl;
    split1(c, ch, cl);
    split1(-s, sh, sl);
    int u0 = ((ks * 8 + mt) * 64 + lane0) * 8 + j;
    THs[u0] = ch;  TLs[u0] = cl;
    THs[u0 + 8] = sh;  TLs[u0 + 8] = sl;
}

#define MM(A, B, C) C = __builtin_amdgcn_mfma_f32_16x16x32_bf16(A, B, C, 0, 0, 0)

// ---------------- kernel 1: truncated DFT via MFMA (unchanged) ----------
__global__ __launch_bounds__(512) void k_dft4(const float* __restrict__ q,
                                              float* __restrict__ dout) {
    __shared__ float qs[2 * 2048];      // 16KB: [buf][lp 64][h 32]
    const int t    = threadIdx.x;
    const int wave = t >> 6;
    const int lane = t & 63;
    const int a    = wave & 3;
    const int ht   = wave >> 2;
    const int b    = blockIdx.x >> 4;
    const int hg   = blockIdx.x & 15;
    const int hbase = hg * 32;
    const int col  = lane & 15;
    const int kg   = lane >> 4;
    const float* qb = q + (size_t)b * BCHUNK;
    const int4* TH4 = (const int4*)dout;
    const int4* TL4 = (const int4*)(dout + 65536);

    f32x4 acc[2] = {{0.f, 0.f, 0.f, 0.f}, {0.f, 0.f, 0.f, 0.f}};
    const int lp = wave * 8 + (lane >> 3);     // slot row for gload src
    const int hq = 4 * (lane & 7);

    gload16(qb + (size_t)lp * EQ + hbase + hq, &qs[wave * 256]);

    int cur = 0;
    for (int cc = 0; cc < 16; ++cc) {
        __syncthreads();                        // q(cc) ready in buf[cur]
        FragI ah[2][2], al[2][2];
#pragma unroll
        for (int ksl = 0; ksl < 2; ++ksl)
#pragma unroll
            for (int ti = 0; ti < 2; ++ti) {
                int idx = ((cc * 2 + ksl) * 8 + 2 * a + ti) * 64 + lane;
                ah[ksl][ti].v = TH4[idx];
                al[ksl][ti].v = TL4[idx];
            }
        if (cc < 15)
            gload16(qb + (size_t)((cc + 1) * 64 + lp) * EQ + hbase + hq,
                    &qs[(cur ^ 1) * 2048 + wave * 256]);
#pragma unroll
        for (int ksl = 0; ksl < 2; ++ksl) {
            float v[8];
#pragma unroll
            for (int j = 0; j < 8; ++j)
                v[j] = qs[cur * 2048 + (ksl * 32 + kg * 8 + j) * 32 + ht * 16 + col];
            FragI bhiF, bloF;
#pragma unroll
            for (int k2 = 0; k2 < 4; ++k2) {
                unsigned h_, l_;
                split2(v[2 * k2], v[2 * k2 + 1], h_, l_);
                bhiF.i[k2] = (int)h_;
                bloF.i[k2] = (int)l_;
            }
#pragma unroll
            for (int ti = 0; ti < 2; ++ti) {
                MM(ah[ksl][ti].s, bhiF.s, acc[ti]);
                MM(ah[ksl][ti].s, bloF.s, acc[ti]);
                MM(al[ksl][ti].s, bhiF.s, acc[ti]);
            }
        }
        cur ^= 1;
    }
    const int h = hbase + ht * 16 + col;
#pragma unroll
    for (int ti = 0; ti < 2; ++ti) {
        int mt = 2 * a + ti;
        int mA = mt * 8 + kg * 2;
#pragma unroll
        for (int mi = 0; mi < 2; ++mi) {
            float xr = acc[ti][2 * mi];
            float xi = acc[ti][2 * mi + 1];
            ushort_t rh, rl, ih_, il_;
            split1(xr, rh, rl);
            split1(xi, ih_, il_);
            int m = mA + mi;
            *(ushort_t*)sx_ptr(dout, 0, m, b, h) = rh;
            *(ushort_t*)sx_ptr(dout, 1, m, b, h) = rl;
            *(ushort_t*)sx_ptr(dout, 2, m, b, h) = ih_;
            *(ushort_t*)sx_ptr(dout, 3, m, b, h) = il_;
        }
    }
}

// ---------------- kernel 2: per-mode complex GEMM, v15 ----------------
// Opart[hs][b][2m+ri][i] = sum_{h in hs quarter} X[b][h][m] * W[h][i][m]
// grid 256 = hs(4) x mc(4: 16m) x it(16: 32 i). block 1024 = 16 waves,
// wave w -> SINGLE mode m0+w, BOTH i-subtiles. Register budget fits the
// 128-VGPR hard cap: acc[isub][part][nt]=32, st=32, bX(nt-outer,shared
// across isubs)=16, aW=16 with in-place negation. X line-requests halved
// vs r13 (bX consumed by both isubs); W dense read-once; O unchanged.
// Per-acc MFMA order identical to r13 -> bit-identical output.
__global__ __launch_bounds__(1024) void k_modes14(const float* __restrict__ wreal,
                                                  const float* __restrict__ wimag,
                                                  float* __restrict__ dout) {
    __shared__ float Wlds[2 * 32 * 32 * 18];   // 147456 B
    const int t    = threadIdx.x;
    const int wave = t >> 6;             // 0..15 = m within mc group
    const int lane = t & 63;
    const int blk  = blockIdx.x;
    const int hs   = blk >> 6;           // 0..3
    const int mc   = (blk >> 4) & 3;
    const int it   = blk & 15;
    const int i0   = it * 32;
    const int m0   = mc * 16;
    const int col  = lane & 15;          // A row (i within subtile) / B col (b)
    const int kg   = lane >> 4;          // k-group
    const int hbase = hs * 128;
    const int mloc = wave;

    const char* xp0 = sx_ptr(dout, 0, m0 + wave, col, hbase + kg * 8);

    f32x4 zero4 = {0.f, 0.f, 0.f, 0.f};
    f32x4 acc[2][2][2];                  // [isub][part][nt] = 32 VGPR
#pragma unroll
    for (int s_ = 0; s_ < 2; ++s_)
#pragma unroll
        for (int bq = 0; bq < 2; ++bq)
#pragma unroll
            for (int c = 0; c < 2; ++c) acc[s_][bq][c] = zero4;

    float2 st[16];                       // staging regs (32 VGPR)
#define LOADK(KK)                                                             \
    {                                                                         \
        int h0_ = hbase + (KK) * 32;                                          \
        _Pragma("unroll")                                                     \
        for (int r = 0; r < 16; ++r) {                                        \
            int e = r * 1024 + t;                                             \
            int m2 = e & 7, ii = (e >> 3) & 31, hh = (e >> 8) & 31;           \
            const float* src = (e >> 13) ? wimag : wreal;                     \
            st[r] = *(const float2*)&src[(size_t)(h0_ + hh) * 32768 +         \
                                         (size_t)(i0 + ii) * 64 + m0 + 2 * m2]; \
        }                                                                     \
    }

    LOADK(0);
    for (int kk = 0; kk < 4; ++kk) {
#pragma unroll
        for (int r = 0; r < 16; ++r) {
            int e = r * 1024 + t;
            int m2 = e & 7, ii = (e >> 3) & 31, hh = (e >> 8) & 31;
            int part = e >> 13;
            *(float2*)&Wlds[(((part * 32 + hh) * 32) + ii) * 18 + 2 * m2] = st[r];
        }
        __syncthreads();
        if (kk < 3) LOADK(kk + 1);       // prefetch next chunk under compute
#pragma unroll
        for (int nt = 0; nt < 2; ++nt) {
            // X for this (nt,kk): shared across both isubs (the X-halving)
            FragI bX[4];
            const char* xpm = xp0 + (size_t)kk * 2048 + (size_t)nt * 1024;
#pragma unroll
            for (int arr = 0; arr < 4; ++arr)
                bX[arr].v = *(const int4*)(xpm + (size_t)arr * 4194304);
#pragma unroll
            for (int isub = 0; isub < 2; ++isub) {
                short8 aW[2][2];         // [part][prec]: 0=Wr 1=Wi
#pragma unroll
                for (int part = 0; part < 2; ++part) {
                    float v[8];
#pragma unroll
                    for (int j = 0; j < 8; ++j)
                        v[j] = Wlds[((part * 32 + kg * 8 + j) * 32 +
                                     isub * 16 + col) * 18 + mloc];
                    FragI hiF, loF;
#pragma unroll
                    for (int k = 0; k < 4; ++k) {
                        unsigned h, l;
                        split2(v[2 * k], v[2 * k + 1], h, l);
                        hiF.i[k] = (int)h;
                        loF.i[k] = (int)l;
                    }
                    aW[part][0] = hiF.s;
                    aW[part][1] = loF.s;
                }
                // out_i = Wr*xi + Wi*xr   (same per-acc op order as r13)
                MM(aW[0][0], bX[2].s, acc[isub][1][nt]);
                MM(aW[0][0], bX[3].s, acc[isub][1][nt]);
                MM(aW[0][1], bX[2].s, acc[isub][1][nt]);
                MM(aW[1][0], bX[0].s, acc[isub][1][nt]);
                MM(aW[1][0], bX[1].s, acc[isub][1][nt]);
                MM(aW[1][1], bX[0].s, acc[isub][1][nt]);
                // negate Wi in place (exact bf16 sign flip)
                FragI nh, nl;
                nh.s = aW[1][0];
                nl.s = aW[1][1];
#pragma unroll
                for (int k = 0; k < 4; ++k) {
                    nh.i[k] ^= 0x80008000;
                    nl.i[k] ^= 0x80008000;
                }
                // out_r = Wr*xr + (-Wi)*xi
                MM(aW[0][0], bX[0].s, acc[isub][0][nt]);
                MM(aW[0][0], bX[1].s, acc[isub][0][nt]);
                MM(aW[0][1], bX[0].s, acc[isub][0][nt]);
                MM(nh.s,     bX[2].s, acc[isub][0][nt]);
                MM(nh.s,     bX[3].s, acc[isub][0][nt]);
                MM(nl.s,     bX[2].s, acc[isub][0][nt]);
            }
        }
        __syncthreads();
    }
#undef LOADK
    // epilogue: D row = i = i0 + isub*16 + kg*4 + reg (contig float4), col = b
#pragma unroll
    for (int isub = 0; isub < 2; ++isub)
#pragma unroll
        for (int part = 0; part < 2; ++part)
#pragma unroll
            for (int nt = 0; nt < 2; ++nt) {
                int bb = nt * 16 + col;
                int c = 2 * (m0 + wave) + part;
                f32x4 vv = acc[isub][part][nt];
                float4 o = make_float4(vv.x, vv.y, vv.z, vv.w);
                *(float4*)&dout[(size_t)bb * BCHUNK + (size_t)hs * 65536 +
                                (size_t)c * EQ + i0 + isub * 16 + kg * 4] = o;
            }
}

// ---------------- kernel 3: truncated irfft via MFMA (unchanged) ----------
__global__ __launch_bounds__(256) void k_inv3(const unsigned* __restrict__ BFhi,
                                              const unsigned* __restrict__ BFlo,
                                              float* __restrict__ dout) {
    __shared__ unsigned Bf[4096];   // [hilo(2)][nt(2)][kb(4)][lane(64)][4] 16KB
    const int t    = threadIdx.x;
    const int wave = t >> 6;
    const int lane = t & 63;
    const int b    = blockIdx.x >> 4;
    const int it   = blockIdx.x & 15;
    const int i0   = it * 32;
    float* base = dout + (size_t)b * BCHUNK;

#pragma unroll
    for (int r = 0; r < 8; ++r) {
        int idx = r * 256 + t;               // 2048 = 64 c-pairs x 32 i
        int il = idx & 31, cp = idx >> 5;
        int c0 = 2 * cp;
        const float* p0 = base + (size_t)c0 * EQ + i0 + il;
        float s0 = p0[0] + p0[65536] + p0[2 * 65536] + p0[3 * 65536];
        const float* p1 = p0 + EQ;
        float s1 = p1[0] + p1[65536] + p1[2 * 65536] + p1[3 * 65536];
        unsigned hi, lo;
        split2(s0, s1, hi, lo);
        int nt = il >> 4, i_loc = il & 15;
        int kb = c0 >> 5, kg = (c0 & 31) >> 3, jp = (c0 & 7) >> 1;
        int u = (nt * 4 + kb) * 256 + (kg * 16 + i_loc) * 4 + jp;
        Bf[u] = hi;
        Bf[2048 + u] = lo;
    }
    __syncthreads();
    FragI bh[2][4], bl[2][4];
#pragma unroll
    for (int nt = 0; nt < 2; ++nt)
#pragma unroll
        for (int kb = 0; kb < 4; ++kb) {
            bh[nt][kb].v = *(const int4*)&Bf[(nt * 4 + kb) * 256 + lane * 4];
            bl[nt][kb].v = *(const int4*)&Bf[2048 + (nt * 4 + kb) * 256 + lane * 4];
        }
    for (int r = 0; r < 16; ++r) {
        int lt = wave + 4 * r;
        FragI ah[4], al[4];
#pragma unroll
        for (int kb = 0; kb < 4; ++kb) {
            ah[kb].v = *(const int4*)&BFhi[lt * 1024 + kb * 256 + lane * 4];
            al[kb].v = *(const int4*)&BFlo[lt * 1024 + kb * 256 + lane * 4];
        }
        f32x4 a0 = {0.f, 0.f, 0.f, 0.f}, a1 = {0.f, 0.f, 0.f, 0.f};
#pragma unroll
        for (int kb = 0; kb < 4; ++kb) {
            MM(ah[kb].s, bh[0][kb].s, a0);
            MM(ah[kb].s, bl[0][kb].s, a0);
            MM(al[kb].s, bh[0][kb].s, a0);
            MM(ah[kb].s, bh[1][kb].s, a1);
            MM(ah[kb].s, bl[1][kb].s, a1);
            MM(al[kb].s, bh[1][kb].s, a1);
        }
        int lrow = lt * 16 + (lane >> 4) * 4;
        int icol = i0 + (lane & 15);
#pragma unroll
        for (int j = 0; j < 4; ++j) {
            base[(size_t)(lrow + j) * EQ + icol]      = a0[j];
            base[(size_t)(lrow + j) * EQ + icol + 16] = a1[j];
        }
    }
}
#undef MM

extern "C" void kernel_launch(void* const* d_in, const int* in_sizes, int n_in,
                              void* d_out, int out_size, void* d_ws, size_t ws_size,
                              hipStream_t stream) {
    const float* q  = (const float*)d_in[0];
    const float* wr = (const float*)d_in[1];
    const float* wi = (const float*)d_in[2];
    float* out = (float*)d_out;
    unsigned* BFhi = (unsigned*)d_ws;           // u32 [0, 65536)
    unsigned* BFlo = BFhi + 65536;              // u32 [65536, 131072)

    hipLaunchKernelGGL(k_trig,    dim3(256), dim3(256),  0, stream, BFhi, BFlo, out);
    hipLaunchKernelGGL(k_dft4,    dim3(512), dim3(512),  0, stream, q, out);
    hipLaunchKernelGGL(k_modes14, dim3(256), dim3(1024), 0, stream, wr, wi, out);
    hipLaunchKernelGGL(k_inv3,    dim3(512), dim3(256),  0, stream, BFhi, BFlo, out);
}

// Round 17
// 145.950 us; speedup vs baseline: 1.5402x; 1.4827x over previous
//
#include <hip/hip_runtime.h>
#include <math.h>

// Problem constants
#define LQ 1024
#define EQ 512
#define BQ 32
#define MQ 64

static constexpr int BCHUNK = LQ * EQ;   // 524288 floats per b-slice of d_out
// d_out overlay (per b-slice of 524288 floats), phase by phase:
//  k_trig:   Tm bf16 A-frags in slice0 floats [0, 131072)
//  k_dft4:   reads q + Tm-frags; writes SPLITX bf16 arrays 0..3 (sx_ptr) in
//            slices z=0..7 at [z][262144, 524288)  (disjoint from Tm-frags)
//  k_modes15:Opart[hs][c][i] hs=0..3 at b*BCHUNK + hs*65536  [0,262144)
//  k_inv3:   y[l][i] overwrites slice. Each block reads ONLY its own i-columns
//            of the 4 partials (staged to LDS before any write -> WAR-safe).
//
// PERF MODEL (r7..r16, 5-point validated): bound by VMEM line-requests
// (~50 64B-lines/cycle chip-wide; ~9.2us per M-lines). r13: 6.8M -> 71us.
// i-tile 32 halves X re-reads: 4.7M -> ~45us. VGPR cap = 65536/block_threads
// (512thr->128, 1024thr->64); r14-r16 spilled fighting it. Fix: 32x32x16
// MFMA (M=32 covers i-tile in ONE fragment, N=32 covers all b) -> acc 64 +
// aW 16 + bX 16, no staging regs (gload16 with content-level m-quarter XOR
// pre-swizzle; dest linear per m104/m173, READW applies inverse).

typedef short short8 __attribute__((ext_vector_type(8)));
typedef float f32x4 __attribute__((ext_vector_type(4)));
typedef float f32x16 __attribute__((ext_vector_type(16)));
typedef unsigned short ushort_t;

union FragI { int i[4]; int4 v; short8 s; };

// async global->LDS, 16B per lane; dest must be wave-uniform base (+lane*16 HW)
__device__ __forceinline__ void gload16(const float* g, float* l) {
    __builtin_amdgcn_global_load_lds(
        (const __attribute__((address_space(1))) void*)g,
        (__attribute__((address_space(3))) void*)l, 16, 0, 0);
}

// SPLITX: 4 bf16 arrays [m(64)][hblk(16)][b(32)][hh(32)], arr: 0=xrHi 1=xrLo
// 2=xiHi 3=xiLo. Flat bf16 index G = arr*2^20 + m*16384 + (h/32)*1024 + b*32
// + (h%32), mapped into 1MB-float zones: z = G>>19 at slice z offset 262144.
// arr->arr+1 stride = 2 zones = 2 slices = 4194304 bytes.
__device__ inline char* sx_ptr(float* dout, int arr, int m, int b, int h) {
    unsigned G = ((unsigned)arr << 20) + ((unsigned)m << 14) +
                 ((unsigned)(h >> 5) << 10) + ((unsigned)b << 5) + (unsigned)(h & 31);
    unsigned z = G >> 19, w = G & 524287u;
    return (char*)(dout + (size_t)z * BCHUNK + 262144) + (size_t)w * 2;
}

// split two fp32 into packed bf16 pairs (truncation; lo captures the residual)
__device__ inline void split2(float a, float b, unsigned& hi, unsigned& lo) {
    unsigned ua = __float_as_uint(a), ub = __float_as_uint(b);
    unsigned ha = ua & 0xFFFF0000u, hb = ub & 0xFFFF0000u;
    hi = (ua >> 16) | hb;
    float la = a - __uint_as_float(ha);
    float lb = b - __uint_as_float(hb);
    lo = (__float_as_uint(la) >> 16) | (__float_as_uint(lb) & 0xFFFF0000u);
}

__device__ inline void split1(float x, ushort_t& hi, ushort_t& lo) {
    unsigned u = __float_as_uint(x);
    hi = (ushort_t)(u >> 16);
    float r = x - __uint_as_float(u & 0xFFFF0000u);
    lo = (ushort_t)(__float_as_uint(r) >> 16);
}

// ---------------- kernel 0: trig tables (unchanged) ----------------
__global__ __launch_bounds__(256) void k_trig(unsigned* __restrict__ BFhi,
                                              unsigned* __restrict__ BFlo,
                                              float* __restrict__ dout) {
    int idx = blockIdx.x * 256 + threadIdx.x;   // 0..65535 = l*64+m
    int l = idx >> 6, m = idx & 63;
    int tt = (l * m) & (LQ - 1);
    float ang = (float)tt * 6.135923151542565e-03f;  // 2*pi/1024
    float s, c;
    sincosf(ang, &s, &c);
    float coef = (m == 0 ? 1.0f : 2.0f) * (1.0f / (float)LQ);
    float b0 = coef * c;
    float b1 = (m == 0) ? 0.0f : (-2.0f / (float)LQ) * s;
    unsigned hi, lo;
    split2(b0, b1, hi, lo);
    {
        int lt = l >> 4, kb = m >> 4, kgb = (m & 15) >> 2;
        int lane = kgb * 16 + (l & 15);
        int u = lt * 1024 + kb * 256 + lane * 4 + (m & 3);
        BFhi[u] = hi;
        BFlo[u] = lo;
    }
    ushort_t* THs = (ushort_t*)dout;
    ushort_t* TLs = (ushort_t*)(dout + 65536);
    int ks = l >> 5, kg = (l >> 3) & 3, j = l & 7;
    int mt = m >> 3;
    int lane0 = kg * 16 + 2 * (m & 7);
    ushort_t ch, cl, sh, sl;
    split1(c, ch, cl);
    split1(-s, sh, sl);
    int u0 = ((ks * 8 + mt) * 64 + lane0) * 8 + j;
    THs[u0] = ch;  TLs[u0] = cl;
    THs[u0 + 8] = sh;  TLs[u0 + 8] = sl;
}

#define MM(A, B, C) C = __builtin_amdgcn_mfma_f32_16x16x32_bf16(A, B, C, 0, 0, 0)
#define MM32(A, B, C) C = __builtin_amdgcn_mfma_f32_32x32x16_bf16(A, B, C, 0, 0, 0)

// ---------------- kernel 1: truncated DFT via MFMA (unchanged r13) --------
__global__ __launch_bounds__(512) void k_dft4(const float* __restrict__ q,
                                              float* __restrict__ dout) {
    __shared__ float qs[2 * 2048];      // 16KB: [buf][lp 64][h 32]
    const int t    = threadIdx.x;
    const int wave = t >> 6;
    const int lane = t & 63;
    const int a    = wave & 3;
    const int ht   = wave >> 2;
    const int b    = blockIdx.x >> 4;
    const int hg   = blockIdx.x & 15;
    const int hbase = hg * 32;
    const int col  = lane & 15;
    const int kg   = lane >> 4;
    const float* qb = q + (size_t)b * BCHUNK;
    const int4* TH4 = (const int4*)dout;
    const int4* TL4 = (const int4*)(dout + 65536);

    f32x4 acc[2] = {{0.f, 0.f, 0.f, 0.f}, {0.f, 0.f, 0.f, 0.f}};
    const int lp = wave * 8 + (lane >> 3);     // slot row for gload src
    const int hq = 4 * (lane & 7);

    gload16(qb + (size_t)lp * EQ + hbase + hq, &qs[wave * 256]);

    int cur = 0;
    for (int cc = 0; cc < 16; ++cc) {
        __syncthreads();                        // q(cc) ready in buf[cur]
        FragI ah[2][2], al[2][2];
#pragma unroll
        for (int ksl = 0; ksl < 2; ++ksl)
#pragma unroll
            for (int ti = 0; ti < 2; ++ti) {
                int idx = ((cc * 2 + ksl) * 8 + 2 * a + ti) * 64 + lane;
                ah[ksl][ti].v = TH4[idx];
                al[ksl][ti].v = TL4[idx];
            }
        if (cc < 15)
            gload16(qb + (size_t)((cc + 1) * 64 + lp) * EQ + hbase + hq,
                    &qs[(cur ^ 1) * 2048 + wave * 256]);
#pragma unroll
        for (int ksl = 0; ksl < 2; ++ksl) {
            float v[8];
#pragma unroll
            for (int j = 0; j < 8; ++j)
                v[j] = qs[cur * 2048 + (ksl * 32 + kg * 8 + j) * 32 + ht * 16 + col];
            FragI bhiF, bloF;
#pragma unroll
            for (int k2 = 0; k2 < 4; ++k2) {
                unsigned h_, l_;
                split2(v[2 * k2], v[2 * k2 + 1], h_, l_);
                bhiF.i[k2] = (int)h_;
                bloF.i[k2] = (int)l_;
            }
#pragma unroll
            for (int ti = 0; ti < 2; ++ti) {
                MM(ah[ksl][ti].s, bhiF.s, acc[ti]);
                MM(ah[ksl][ti].s, bloF.s, acc[ti]);
                MM(al[ksl][ti].s, bhiF.s, acc[ti]);
            }
        }
        cur ^= 1;
    }
    const int h = hbase + ht * 16 + col;
#pragma unroll
    for (int ti = 0; ti < 2; ++ti) {
        int mt = 2 * a + ti;
        int mA = mt * 8 + kg * 2;
#pragma unroll
        for (int mi = 0; mi < 2; ++mi) {
            float xr = acc[ti][2 * mi];
            float xi = acc[ti][2 * mi + 1];
            ushort_t rh, rl, ih_, il_;
            split1(xr, rh, rl);
            split1(xi, ih_, il_);
            int m = mA + mi;
            *(ushort_t*)sx_ptr(dout, 0, m, b, h) = rh;
            *(ushort_t*)sx_ptr(dout, 1, m, b, h) = rl;
            *(ushort_t*)sx_ptr(dout, 2, m, b, h) = ih_;
            *(ushort_t*)sx_ptr(dout, 3, m, b, h) = il_;
        }
    }
}

// ---------------- kernel 2: per-mode complex GEMM, v16 (32x32x16 MFMA) -----
// Opart[hs][b][2m+ri][i] = sum_{h in hs quarter} X[b][h][m] * W[h][i][m]
// grid 256 = hs(4) x mc(4: 16m) x it(16: 32 i). block 512 = 8 waves, wave ->
// m-pair. One 32x32x16 fragment covers M=32 i (whole tile) x N=32 b -> acc
// [mi][ri] = 4 x f32x16 = 64 VGPR, no isub/nt dims. W staged via gload16
// (linear dest) with m-quarter XOR pre-swizzle on the SOURCE; READW reads
// quarter (mq ^ ((i>>1)&3)) -> 4-way LDS conflicts (~free). 64KB x 2 LDS
// double-buffer, dft4's proven prefetch pattern. mi0's X loads issue BEFORE
// STAGE so counted vmcnt waits keep the W prefetch in flight.
__global__ __launch_bounds__(512) void k_modes15(const float* __restrict__ wreal,
                                                 const float* __restrict__ wimag,
                                                 float* __restrict__ dout) {
    __shared__ float Wlds[2 * 16384];    // 128KB: [buf][part2][h16][i32][m16]
    const int t    = threadIdx.x;
    const int wave = t >> 6;
    const int lane = t & 63;
    const int blk  = blockIdx.x;
    const int hs   = blk >> 6;           // 0..3
    const int mc   = (blk >> 4) & 3;
    const int it   = blk & 15;
    const int i0   = it * 32;
    const int m0   = mc * 16;
    const int hbase = hs * 128;
    const int bcol  = lane & 31;         // B col (b) / A row (i) / D col (b)
    const int khalf = lane >> 5;         // k-group half

    f32x16 acc[2][2];                    // [mi][ri] = 64 VGPR
    {
        f32x16 z;
#pragma unroll
        for (int k = 0; k < 16; ++k) z[k] = 0.0f;
        acc[0][0] = z; acc[0][1] = z; acc[1][0] = z; acc[1][1] = z;
    }

    // STAGE: 8 gload16/wave fill one 64KB buffer: slot s = [part][hh][ihalf],
    // lane covers (i = ihalf*16 + lane>>2, dest m-quarter = lane&3) whose
    // CONTENT is source quarter (lane&3) ^ ((i>>1)&3)  [involution].
#define STAGE(KK, BUF)                                                        \
    {                                                                         \
        _Pragma("unroll")                                                     \
        for (int r = 0; r < 8; ++r) {                                         \
            const int s_ = r * 8 + wave;                                      \
            const int part_ = s_ >> 5;                                        \
            const int hh_ = (s_ >> 1) & 15;                                   \
            const int il_ = (s_ & 1) * 16 + (lane >> 2);                      \
            const int mqs_ = (lane & 3) ^ ((il_ >> 1) & 3);                   \
            const float* src_ = (part_ ? wimag : wreal) +                     \
                (size_t)(hbase + (KK) * 16 + hh_) * 32768 +                   \
                (size_t)(i0 + il_) * 64 + m0 + mqs_ * 4;                      \
            gload16(src_, &Wlds[(BUF) * 16384 + s_ * 256]);                   \
        }                                                                     \
    }

    STAGE(0, 0);
    int cur = 0;
    for (int kk = 0; kk < 8; ++kk) {
        __syncthreads();                 // buf[cur] staged; prev reads done
        // mi0 X loads FIRST (older than STAGE in vmcnt queue)
        FragI x0, x1;
        const char* xpA = sx_ptr(dout, 0, m0 + 2 * wave, bcol,
                                 hbase + kk * 16 + khalf * 8);
        x0.v = *(const int4*)(xpA);                  // xrHi
        x1.v = *(const int4*)(xpA + 4194304);        // xrLo
        if (kk < 7) STAGE(kk + 1, cur ^ 1);          // W prefetch (stays in flight)
#pragma unroll
        for (int mi = 0; mi < 2; ++mi) {
            const int mloc = 2 * wave + mi;
            const int mq = mloc >> 2, m1 = mloc & 3;
            const int qd = ((mq ^ ((bcol >> 1) & 3)) << 2) + m1;
            // A-frags: W hi/lo both parts from LDS
            short8 aW[2][2];
#pragma unroll
            for (int part = 0; part < 2; ++part) {
                float v[8];
#pragma unroll
                for (int j = 0; j < 8; ++j)
                    v[j] = Wlds[cur * 16384 +
                                ((part * 16 + khalf * 8 + j) * 32 + bcol) * 16 + qd];
                FragI hiF, loF;
#pragma unroll
                for (int k2 = 0; k2 < 4; ++k2) {
                    unsigned h_, l_;
                    split2(v[2 * k2], v[2 * k2 + 1], h_, l_);
                    hiF.i[k2] = (int)h_;
                    loF.i[k2] = (int)l_;
                }
                aW[part][0] = hiF.s;
                aW[part][1] = loF.s;
            }
            if (mi == 1) {               // mi1 X loads (xr pair)
                const char* xpB = sx_ptr(dout, 0, m0 + 2 * wave + 1, bcol,
                                         hbase + kk * 16 + khalf * 8);
                x0.v = *(const int4*)(xpB);
                x1.v = *(const int4*)(xpB + 4194304);
            }
            // xr phase: out_r += Wr*xr ; out_i += Wi*xr
            MM32(aW[0][0], x0.s, acc[mi][0]);
            MM32(aW[0][0], x1.s, acc[mi][0]);
            MM32(aW[0][1], x0.s, acc[mi][0]);
            MM32(aW[1][0], x0.s, acc[mi][1]);
            MM32(aW[1][0], x1.s, acc[mi][1]);
            MM32(aW[1][1], x0.s, acc[mi][1]);
            // xi phase
            {
                const char* xpI = sx_ptr(dout, 2, m0 + 2 * wave + mi, bcol,
                                         hbase + kk * 16 + khalf * 8);
                x0.v = *(const int4*)(xpI);              // xiHi
                x1.v = *(const int4*)(xpI + 4194304);    // xiLo
            }
            MM32(aW[0][0], x0.s, acc[mi][1]);
            MM32(aW[0][0], x1.s, acc[mi][1]);
            MM32(aW[0][1], x0.s, acc[mi][1]);
            // negate Wi in place (exact bf16 sign flip)
            FragI nh, nl;
            nh.s = aW[1][0];
            nl.s = aW[1][1];
#pragma unroll
            for (int k2 = 0; k2 < 4; ++k2) {
                nh.i[k2] ^= 0x80008000;
                nl.i[k2] ^= 0x80008000;
            }
            MM32(nh.s, x0.s, acc[mi][0]);
            MM32(nh.s, x1.s, acc[mi][0]);
            MM32(nl.s, x0.s, acc[mi][0]);
        }
        cur ^= 1;
    }
#undef STAGE
    // epilogue: D col = b = lane&31; row = (reg&3) + 8*(reg>>2) + 4*khalf
    // [verified m74/m101] -> 4 contiguous-float4 writes per acc tile.
#pragma unroll
    for (int mi = 0; mi < 2; ++mi)
#pragma unroll
        for (int ri = 0; ri < 2; ++ri) {
            int c = 2 * (m0 + 2 * wave + mi) + ri;
#pragma unroll
            for (int qd = 0; qd < 4; ++qd) {
                int irow = i0 + 8 * qd + 4 * khalf;
                float4 o = make_float4(acc[mi][ri][4 * qd + 0],
                                       acc[mi][ri][4 * qd + 1],
                                       acc[mi][ri][4 * qd + 2],
                                       acc[mi][ri][4 * qd + 3]);
                *(float4*)&dout[(size_t)bcol * BCHUNK + (size_t)hs * 65536 +
                                (size_t)c * EQ + irow] = o;
            }
        }
}

// ---------------- kernel 3: truncated irfft via MFMA (unchanged) ----------
__global__ __launch_bounds__(256) void k_inv3(const unsigned* __restrict__ BFhi,
                                              const unsigned* __restrict__ BFlo,
                                              float* __restrict__ dout) {
    __shared__ unsigned Bf[4096];   // [hilo(2)][nt(2)][kb(4)][lane(64)][4] 16KB
    const int t    = threadIdx.x;
    const int wave = t >> 6;
    const int lane = t & 63;
    const int b    = blockIdx.x >> 4;
    const int it   = blockIdx.x & 15;
    const int i0   = it * 32;
    float* base = dout + (size_t)b * BCHUNK;

#pragma unroll
    for (int r = 0; r < 8; ++r) {
        int idx = r * 256 + t;               // 2048 = 64 c-pairs x 32 i
        int il = idx & 31, cp = idx >> 5;
        int c0 = 2 * cp;
        const float* p0 = base + (size_t)c0 * EQ + i0 + il;
        float s0 = p0[0] + p0[65536] + p0[2 * 65536] + p0[3 * 65536];
        const float* p1 = p0 + EQ;
        float s1 = p1[0] + p1[65536] + p1[2 * 65536] + p1[3 * 65536];
        unsigned hi, lo;
        split2(s0, s1, hi, lo);
        int nt = il >> 4, i_loc = il & 15;
        int kb = c0 >> 5, kg = (c0 & 31) >> 3, jp = (c0 & 7) >> 1;
        int u = (nt * 4 + kb) * 256 + (kg * 16 + i_loc) * 4 + jp;
        Bf[u] = hi;
        Bf[2048 + u] = lo;
    }
    __syncthreads();
    FragI bh[2][4], bl[2][4];
#pragma unroll
    for (int nt = 0; nt < 2; ++nt)
#pragma unroll
        for (int kb = 0; kb < 4; ++kb) {
            bh[nt][kb].v = *(const int4*)&Bf[(nt * 4 + kb) * 256 + lane * 4];
            bl[nt][kb].v = *(const int4*)&Bf[2048 + (nt * 4 + kb) * 256 + lane * 4];
        }
    for (int r = 0; r < 16; ++r) {
        int lt = wave + 4 * r;
        FragI ah[4], al[4];
#pragma unroll
        for (int kb = 0; kb < 4; ++kb) {
            ah[kb].v = *(const int4*)&BFhi[lt * 1024 + kb * 256 + lane * 4];
            al[kb].v = *(const int4*)&BFlo[lt * 1024 + kb * 256 + lane * 4];
        }
        f32x4 a0 = {0.f, 0.f, 0.f, 0.f}, a1 = {0.f, 0.f, 0.f, 0.f};
#pragma unroll
        for (int kb = 0; kb < 4; ++kb) {
            MM(ah[kb].s, bh[0][kb].s, a0);
            MM(ah[kb].s, bl[0][kb].s, a0);
            MM(al[kb].s, bh[0][kb].s, a0);
            MM(ah[kb].s, bh[1][kb].s, a1);
            MM(ah[kb].s, bl[1][kb].s, a1);
            MM(al[kb].s, bh[1][kb].s, a1);
        }
        int lrow = lt * 16 + (lane >> 4) * 4;
        int icol = i0 + (lane & 15);
#pragma unroll
        for (int j = 0; j < 4; ++j) {
            base[(size_t)(lrow + j) * EQ + icol]      = a0[j];
            base[(size_t)(lrow + j) * EQ + icol + 16] = a1[j];
        }
    }
}
#undef MM
#undef MM32

extern "C" void kernel_launch(void* const* d_in, const int* in_sizes, int n_in,
                              void* d_out, int out_size, void* d_ws, size_t ws_size,
                              hipStream_t stream) {
    const float* q  = (const float*)d_in[0];
    const float* wr = (const float*)d_in[1];
    const float* wi = (const float*)d_in[2];
    float* out = (float*)d_out;
    unsigned* BFhi = (unsigned*)d_ws;           // u32 [0, 65536)
    unsigned* BFlo = BFhi + 65536;              // u32 [65536, 131072)

    hipLaunchKernelGGL(k_trig,    dim3(256), dim3(256), 0, stream, BFhi, BFlo, out);
    hipLaunchKernelGGL(k_dft4,    dim3(512), dim3(512), 0, stream, q, out);
    hipLaunchKernelGGL(k_modes15, dim3(256), dim3(512), 0, stream, wr, wi, out);
    hipLaunchKernelGGL(k_inv3,    dim3(512), dim3(256), 0, stream, BFhi, BFlo, out);
}